// Round 4
// baseline (815.305 us; speedup 1.0000x reference)
//
#include <hip/hip_runtime.h>
#include <hip/hip_bf16.h>

typedef __bf16 bf16x8 __attribute__((ext_vector_type(8)));
typedef float  f32x4  __attribute__((ext_vector_type(4)));

#define NGENE  16384
#define NREG   8192
#define DMODEL 256
#define ODIM   128
#define KSPLIT 8
#define KCHUNK (NGENE / KSPLIT)      // 2048
#define NSTEP  (KCHUNK / 32)         // 64
#define ALPHA  0.2f

__device__ __forceinline__ float bf2f(unsigned short u) {
  union { unsigned int i; float f; } v; v.i = ((unsigned int)u) << 16; return v.f;
}
__device__ __forceinline__ unsigned short f2bf(float f) {
  __bf16 b = (__bf16)f;
  return __builtin_bit_cast(unsigned short, b);
}

// ---------- dtype detector: adj values are exactly 0.0/1.0 ------------------
// f32 storage: low16 of every u32 word is 0x0000; bf16 storage: low16 is a
// bf16 element (=0x3F80 w.p. ~1/2 per word). 1024 words -> certainty.
__global__ void k_detect(const unsigned int* __restrict__ adj_raw,
                         int* __restrict__ flag) {
  int found = 0;
  for (int i = threadIdx.x; i < 1024; i += 64)
    if ((adj_raw[i] & 0xffffu) == 0x3f80u) found = 1;
  int any = __any(found) ? 1 : 0;
  if (threadIdx.x == 0) *flag = any;
}

// ---------- canon W -> WT bf16 [128][256]; AV -> f32[256] -------------------
__global__ void k_wt(const void* __restrict__ W, const void* __restrict__ AVin,
                     const int* __restrict__ flag,
                     unsigned short* __restrict__ WT,
                     float* __restrict__ AVf) {
  const int n = blockIdx.x, k = threadIdx.x;
  const int bf = *flag;
  float w = bf ? bf2f(((const unsigned short*)W)[k * ODIM + n])
               : ((const float*)W)[k * ODIM + n];
  WT[n * DMODEL + k] = f2bf(w);
  if (n == 0)
    AVf[k] = bf ? bf2f(((const unsigned short*)AVin)[k]) : ((const float*)AVin)[k];
}

// ---------- w_h = X@W ; WhT bf16 [128][16384]; w1,w2 f32 --------------------
__global__ __launch_bounds__(256) void k_wh(
    const void* __restrict__ X, const int* __restrict__ flag,
    const unsigned short* __restrict__ WT, const float* __restrict__ AVf,
    unsigned short* __restrict__ WhT,
    float* __restrict__ w1, float* __restrict__ w2) {
  __shared__ float lds[4][16][ODIM + 1];
  const int tid = threadIdx.x;
  const int w = tid >> 6, l = tid & 63;
  const int q = l >> 4, ln = l & 15;
  const int m0 = blockIdx.x * 64 + w * 16;

  f32x4 acc[8];
#pragma unroll
  for (int t = 0; t < 8; ++t) acc[t] = (f32x4){0.f, 0.f, 0.f, 0.f};

  const int bf = *flag;
#pragma unroll
  for (int ks = 0; ks < 8; ++ks) {
    const int k0 = ks * 32 + q * 8;
    bf16x8 a;
    if (bf) {
      a = *(const bf16x8*)((const unsigned short*)X + (size_t)(m0 + ln) * DMODEL + k0);
    } else {
      const float* xp = (const float*)X + (size_t)(m0 + ln) * DMODEL + k0;
      f32x4 x0 = *(const f32x4*)xp, x1 = *(const f32x4*)(xp + 4);
#pragma unroll
      for (int j = 0; j < 8; ++j) a[j] = (__bf16)((j < 4) ? x0[j] : x1[j - 4]);
    }
#pragma unroll
    for (int t = 0; t < 8; ++t) {
      bf16x8 b = *(const bf16x8*)(WT + (size_t)(16 * t + ln) * DMODEL + k0);
      acc[t] = __builtin_amdgcn_mfma_f32_16x16x32_bf16(a, b, acc[t], 0, 0, 0);
    }
  }

  // w1/w2 dot products with f32 a_values
  float a1v[8], a2v[8];
#pragma unroll
  for (int t = 0; t < 8; ++t) {
    a1v[t] = AVf[16 * t + ln];
    a2v[t] = AVf[ODIM + 16 * t + ln];
  }
#pragma unroll
  for (int r = 0; r < 4; ++r) {
    float s1 = 0.f, s2 = 0.f;
#pragma unroll
    for (int t = 0; t < 8; ++t) {
      s1 += acc[t][r] * a1v[t];
      s2 += acc[t][r] * a2v[t];
    }
    s1 += __shfl_xor(s1, 1); s1 += __shfl_xor(s1, 2);
    s1 += __shfl_xor(s1, 4); s1 += __shfl_xor(s1, 8);
    s2 += __shfl_xor(s2, 1); s2 += __shfl_xor(s2, 2);
    s2 += __shfl_xor(s2, 4); s2 += __shfl_xor(s2, 8);
    const int row = m0 + q * 4 + r;
    if (ln == 0) {
      w2[row] = s2;
      if (row < NREG) w1[row] = s1;
    }
  }

  // transpose via LDS -> WhT bf16
#pragma unroll
  for (int t = 0; t < 8; ++t)
#pragma unroll
    for (int r = 0; r < 4; ++r)
      lds[w][q * 4 + r][16 * t + ln] = acc[t][r];
  __syncthreads();

#pragma unroll
  for (int rr = 0; rr < 2; ++rr) {
    const int n = 2 * l + rr;
    unsigned short oh[16];
#pragma unroll
    for (int m = 0; m < 16; ++m) oh[m] = f2bf(lds[w][m][n]);
    uint4* dh = (uint4*)(WhT + (size_t)n * NGENE + m0);
    dh[0] = ((uint4*)oh)[0]; dh[1] = ((uint4*)oh)[1];
  }
}

// ---------- fused masked exp-GEMM, barrier-free -----------------------------
// block: 256 thr = 4 waves; each wave independently covers 32 m-rows x KCHUNK.
// B fragments come straight from WhT (4 MB, L2/L3-resident) -> no LDS, no
// __syncthreads, adj prefetch pipelines freely with fine-grained vmcnt.
__global__ __launch_bounds__(256, 2) void k_att(
    const void* __restrict__ adj, const int* __restrict__ flag,
    const unsigned short* __restrict__ WhT,
    const float* __restrict__ w1, const float* __restrict__ w2,
    float* __restrict__ Opart, float* __restrict__ Spart) {
  const int tid = threadIdx.x;
  const int w = tid >> 6, l = tid & 63;
  const int q = l >> 4, ln = l & 15;
  const int mb = blockIdx.x & 63;
  const int kc = blockIdx.x >> 6;
  const int m0 = mb * 128 + w * 32;
  const int r0 = m0 + ln, r1 = m0 + 16 + ln;
  const int kbase = kc * KCHUNK;

  const float w1v0 = w1[r0], w1v1 = w1[r1];

  const unsigned short* bpt[8];
#pragma unroll
  for (int t = 0; t < 8; ++t)
    bpt[t] = WhT + (size_t)(16 * t + ln) * NGENE + kbase + q * 8;

  f32x4 acc0[8], acc1[8];
#pragma unroll
  for (int t = 0; t < 8; ++t) {
    acc0[t] = (f32x4){0.f, 0.f, 0.f, 0.f};
    acc1[t] = (f32x4){0.f, 0.f, 0.f, 0.f};
  }
  float ssum0 = 0.f, ssum1 = 0.f;
  const float* wp = w2 + kbase + q * 8;

  if (*flag) {   // -------- bf16 adjacency --------
    const unsigned short* A = (const unsigned short*)adj;
    const unsigned short* ap0 = A + (size_t)r0 * NGENE + kbase + q * 8;
    const unsigned short* ap1 = A + (size_t)r1 * NGENE + kbase + q * 8;
    uint4 c0[2], c1[2]; f32x4 wa[2], wb[2];
#pragma unroll
    for (int i = 0; i < 2; ++i) {
      c0[i] = *(const uint4*)(ap0 + i * 32);
      c1[i] = *(const uint4*)(ap1 + i * 32);
      wa[i] = *(const f32x4*)(wp + i * 32);
      wb[i] = *(const f32x4*)(wp + i * 32 + 4);
    }
#pragma unroll 2
    for (int st = 0; st < NSTEP; ++st) {
      const int cur = st & 1;
      uint4 u0 = c0[cur], u1 = c1[cur];
      f32x4 va = wa[cur], vb = wb[cur];
      if (st + 2 < NSTEP) {
        c0[cur] = *(const uint4*)(ap0 + (st + 2) * 32);
        c1[cur] = *(const uint4*)(ap1 + (st + 2) * 32);
        wa[cur] = *(const f32x4*)(wp + (st + 2) * 32);
        wb[cur] = *(const f32x4*)(wp + (st + 2) * 32 + 4);
      }
      bf16x8 bv[8];
#pragma unroll
      for (int t = 0; t < 8; ++t)
        bv[t] = *(const bf16x8*)(bpt[t] + st * 32);

      bf16x8 af0, af1;
      const unsigned int* p0w = (const unsigned int*)&u0;
      const unsigned int* p1w = (const unsigned int*)&u1;
#pragma unroll
      for (int j = 0; j < 8; ++j) {
        union { unsigned int i; float f; } x, y;
        x.i = (j & 1) ? (p0w[j >> 1] & 0xffff0000u) : (p0w[j >> 1] << 16);
        y.i = (j & 1) ? (p1w[j >> 1] & 0xffff0000u) : (p1w[j >> 1] << 16);
        const float w2v = (j < 4) ? va[j] : vb[j - 4];
        float s0 = w1v0 + w2v;
        float p0 = x.f * __expf(fmaxf(s0, ALPHA * s0));
        __bf16 pb0 = (__bf16)p0;
        af0[j] = pb0; ssum0 += (float)pb0;
        float s1 = w1v1 + w2v;
        float p1 = y.f * __expf(fmaxf(s1, ALPHA * s1));
        __bf16 pb1 = (__bf16)p1;
        af1[j] = pb1; ssum1 += (float)pb1;
      }
#pragma unroll
      for (int t = 0; t < 8; ++t) {
        acc0[t] = __builtin_amdgcn_mfma_f32_16x16x32_bf16(af0, bv[t], acc0[t], 0, 0, 0);
        acc1[t] = __builtin_amdgcn_mfma_f32_16x16x32_bf16(af1, bv[t], acc1[t], 0, 0, 0);
      }
    }
  } else {       // -------- f32 adjacency --------
    const float* A = (const float*)adj;
    const float* ap0 = A + (size_t)r0 * NGENE + kbase + q * 8;
    const float* ap1 = A + (size_t)r1 * NGENE + kbase + q * 8;
    f32x4 c0a[2], c0b[2], c1a[2], c1b[2], wa[2], wb[2];
#pragma unroll
    for (int i = 0; i < 2; ++i) {
      c0a[i] = *(const f32x4*)(ap0 + i * 32);
      c0b[i] = *(const f32x4*)(ap0 + i * 32 + 4);
      c1a[i] = *(const f32x4*)(ap1 + i * 32);
      c1b[i] = *(const f32x4*)(ap1 + i * 32 + 4);
      wa[i] = *(const f32x4*)(wp + i * 32);
      wb[i] = *(const f32x4*)(wp + i * 32 + 4);
    }
#pragma unroll 2
    for (int st = 0; st < NSTEP; ++st) {
      const int cur = st & 1;
      f32x4 u0a = c0a[cur], u0b = c0b[cur], u1a = c1a[cur], u1b = c1b[cur];
      f32x4 va = wa[cur], vb = wb[cur];
      if (st + 2 < NSTEP) {
        c0a[cur] = *(const f32x4*)(ap0 + (st + 2) * 32);
        c0b[cur] = *(const f32x4*)(ap0 + (st + 2) * 32 + 4);
        c1a[cur] = *(const f32x4*)(ap1 + (st + 2) * 32);
        c1b[cur] = *(const f32x4*)(ap1 + (st + 2) * 32 + 4);
        wa[cur] = *(const f32x4*)(wp + (st + 2) * 32);
        wb[cur] = *(const f32x4*)(wp + (st + 2) * 32 + 4);
      }
      bf16x8 bv[8];
#pragma unroll
      for (int t = 0; t < 8; ++t)
        bv[t] = *(const bf16x8*)(bpt[t] + st * 32);

      bf16x8 af0, af1;
#pragma unroll
      for (int j = 0; j < 8; ++j) {
        const float a0 = (j < 4) ? u0a[j] : u0b[j - 4];
        const float a1 = (j < 4) ? u1a[j] : u1b[j - 4];
        const float w2v = (j < 4) ? va[j] : vb[j - 4];
        float s0 = w1v0 + w2v;
        float p0 = a0 * __expf(fmaxf(s0, ALPHA * s0));
        __bf16 pb0 = (__bf16)p0;
        af0[j] = pb0; ssum0 += (float)pb0;
        float s1 = w1v1 + w2v;
        float p1 = a1 * __expf(fmaxf(s1, ALPHA * s1));
        __bf16 pb1 = (__bf16)p1;
        af1[j] = pb1; ssum1 += (float)pb1;
      }
#pragma unroll
      for (int t = 0; t < 8; ++t) {
        acc0[t] = __builtin_amdgcn_mfma_f32_16x16x32_bf16(af0, bv[t], acc0[t], 0, 0, 0);
        acc1[t] = __builtin_amdgcn_mfma_f32_16x16x32_bf16(af1, bv[t], acc1[t], 0, 0, 0);
      }
    }
  }

  ssum0 += __shfl_xor(ssum0, 16); ssum0 += __shfl_xor(ssum0, 32);
  ssum1 += __shfl_xor(ssum1, 16); ssum1 += __shfl_xor(ssum1, 32);
  if (l < 16) {
    Spart[(size_t)kc * NREG + r0] = ssum0;
    Spart[(size_t)kc * NREG + r1] = ssum1;
  }
  float* op0 = Opart + ((size_t)kc * NREG + m0) * ODIM;
  float* op1 = op0 + 16 * ODIM;
#pragma unroll
  for (int t = 0; t < 8; ++t)
#pragma unroll
    for (int r = 0; r < 4; ++r) {
      op0[(q * 4 + r) * ODIM + 16 * t + ln] = acc0[t][r];
      op1[(q * 4 + r) * ODIM + 16 * t + ln] = acc1[t][r];
    }
}

// ---------- reduce splits, normalize, ELU, emit per detected dtype ----------
__global__ void k_red(const float* __restrict__ Opart,
                      const float* __restrict__ Spart,
                      const int* __restrict__ flag, void* __restrict__ out) {
  const int id = blockIdx.x * 256 + threadIdx.x;
  const int row = id >> 7;
  float o = 0.f, s = 0.f;
#pragma unroll
  for (int k = 0; k < KSPLIT; ++k) {
    o += Opart[(size_t)k * (NREG * ODIM) + id];
    s += Spart[(size_t)k * NREG + row];
  }
  const float r = o / s;
  const float res = r > 0.f ? r : (__expf(r) - 1.f);
  if (*flag) ((unsigned short*)out)[id] = f2bf(res);
  else       ((float*)out)[id] = res;
}

extern "C" void kernel_launch(void* const* d_in, const int* in_sizes, int n_in,
                              void* d_out, int out_size, void* d_ws, size_t ws_size,
                              hipStream_t stream) {
  const void* X   = d_in[0];
  const void* ADJ = d_in[1];
  const void* W   = d_in[2];
  const void* AV  = d_in[3];

  char* ws = (char*)d_ws;
  size_t off = 0;
  auto alloc = [&](size_t bytes) -> void* {
    void* p = ws + off; off += (bytes + 255) & ~(size_t)255; return p;
  };
  unsigned short* WhT = (unsigned short*)alloc((size_t)ODIM * NGENE * 2);
  unsigned short* WT  = (unsigned short*)alloc((size_t)DMODEL * ODIM * 2);
  float* AVf   = (float*)alloc(2 * ODIM * 4);
  float* w1    = (float*)alloc((size_t)NREG * 4);
  float* w2    = (float*)alloc((size_t)NGENE * 4);
  int*   flag  = (int*)alloc(256);
  float* Spart = (float*)alloc((size_t)KSPLIT * NREG * 4);
  float* Opart = (float*)alloc((size_t)KSPLIT * NREG * ODIM * 4);

  hipLaunchKernelGGL(k_detect, dim3(1), dim3(64), 0, stream,
                     (const unsigned int*)ADJ, flag);
  hipLaunchKernelGGL(k_wt, dim3(ODIM), dim3(DMODEL), 0, stream,
                     W, AV, flag, WT, AVf);
  hipLaunchKernelGGL(k_wh, dim3(NGENE / 64), dim3(256), 0, stream,
                     X, flag, WT, AVf, WhT, w1, w2);
  hipLaunchKernelGGL(k_att, dim3(64 * KSPLIT), dim3(256), 0, stream,
                     ADJ, flag, WhT, w1, w2, Opart, Spart);
  hipLaunchKernelGGL(k_red, dim3((NREG * ODIM) / 256), dim3(256), 0, stream,
                     Opart, Spart, flag, d_out);
}

// Round 5
// 801.684 us; speedup vs baseline: 1.0170x; 1.0170x over previous
//
#include <hip/hip_runtime.h>
#include <hip/hip_bf16.h>

typedef __bf16 bf16x8 __attribute__((ext_vector_type(8)));
typedef float  f32x4  __attribute__((ext_vector_type(4)));

#define NGENE  16384
#define NREG   8192
#define DMODEL 256
#define ODIM   128
#define KSPLIT 8
#define KCHUNK (NGENE / KSPLIT)      // 2048
#define NSTEP  (KCHUNK / 32)         // 64
#define ALPHA  0.2f

__device__ __forceinline__ float bf2f(unsigned short u) {
  union { unsigned int i; float f; } v; v.i = ((unsigned int)u) << 16; return v.f;
}
__device__ __forceinline__ unsigned short f2bf(float f) {
  __bf16 b = (__bf16)f;
  return __builtin_bit_cast(unsigned short, b);
}

// ---------- dtype detector: adj values are exactly 0.0/1.0 ------------------
__global__ void k_detect(const unsigned int* __restrict__ adj_raw,
                         int* __restrict__ flag) {
  int found = 0;
  for (int i = threadIdx.x; i < 1024; i += 64)
    if ((adj_raw[i] & 0xffffu) == 0x3f80u) found = 1;
  int any = __any(found) ? 1 : 0;
  if (threadIdx.x == 0) *flag = any;
}

// ---------- canon W -> WT bf16 [128][256]; AV -> f32[256] -------------------
__global__ void k_wt(const void* __restrict__ W, const void* __restrict__ AVin,
                     const int* __restrict__ flag,
                     unsigned short* __restrict__ WT,
                     float* __restrict__ AVf) {
  const int n = blockIdx.x, k = threadIdx.x;
  const int bf = *flag;
  float w = bf ? bf2f(((const unsigned short*)W)[k * ODIM + n])
               : ((const float*)W)[k * ODIM + n];
  WT[n * DMODEL + k] = f2bf(w);
  if (n == 0)
    AVf[k] = bf ? bf2f(((const unsigned short*)AVin)[k]) : ((const float*)AVin)[k];
}

// ---------- w_h = X@W ; WhT bf16 [128][16384]; w1,w2 f32 --------------------
__global__ __launch_bounds__(256) void k_wh(
    const void* __restrict__ X, const int* __restrict__ flag,
    const unsigned short* __restrict__ WT, const float* __restrict__ AVf,
    unsigned short* __restrict__ WhT,
    float* __restrict__ w1, float* __restrict__ w2) {
  __shared__ float lds[4][16][ODIM + 1];
  const int tid = threadIdx.x;
  const int w = tid >> 6, l = tid & 63;
  const int q = l >> 4, ln = l & 15;
  const int m0 = blockIdx.x * 64 + w * 16;

  f32x4 acc[8];
#pragma unroll
  for (int t = 0; t < 8; ++t) acc[t] = (f32x4){0.f, 0.f, 0.f, 0.f};

  const int bf = *flag;
#pragma unroll
  for (int ks = 0; ks < 8; ++ks) {
    const int k0 = ks * 32 + q * 8;
    bf16x8 a;
    if (bf) {
      a = *(const bf16x8*)((const unsigned short*)X + (size_t)(m0 + ln) * DMODEL + k0);
    } else {
      const float* xp = (const float*)X + (size_t)(m0 + ln) * DMODEL + k0;
      f32x4 x0 = *(const f32x4*)xp, x1 = *(const f32x4*)(xp + 4);
#pragma unroll
      for (int j = 0; j < 8; ++j) a[j] = (__bf16)((j < 4) ? x0[j] : x1[j - 4]);
    }
#pragma unroll
    for (int t = 0; t < 8; ++t) {
      bf16x8 b = *(const bf16x8*)(WT + (size_t)(16 * t + ln) * DMODEL + k0);
      acc[t] = __builtin_amdgcn_mfma_f32_16x16x32_bf16(a, b, acc[t], 0, 0, 0);
    }
  }

  float a1v[8], a2v[8];
#pragma unroll
  for (int t = 0; t < 8; ++t) {
    a1v[t] = AVf[16 * t + ln];
    a2v[t] = AVf[ODIM + 16 * t + ln];
  }
#pragma unroll
  for (int r = 0; r < 4; ++r) {
    float s1 = 0.f, s2 = 0.f;
#pragma unroll
    for (int t = 0; t < 8; ++t) {
      s1 += acc[t][r] * a1v[t];
      s2 += acc[t][r] * a2v[t];
    }
    s1 += __shfl_xor(s1, 1); s1 += __shfl_xor(s1, 2);
    s1 += __shfl_xor(s1, 4); s1 += __shfl_xor(s1, 8);
    s2 += __shfl_xor(s2, 1); s2 += __shfl_xor(s2, 2);
    s2 += __shfl_xor(s2, 4); s2 += __shfl_xor(s2, 8);
    const int row = m0 + q * 4 + r;
    if (ln == 0) {
      w2[row] = s2;
      if (row < NREG) w1[row] = s1;
    }
  }

#pragma unroll
  for (int t = 0; t < 8; ++t)
#pragma unroll
    for (int r = 0; r < 4; ++r)
      lds[w][q * 4 + r][16 * t + ln] = acc[t][r];
  __syncthreads();

#pragma unroll
  for (int rr = 0; rr < 2; ++rr) {
    const int n = 2 * l + rr;
    unsigned short oh[16];
#pragma unroll
    for (int m = 0; m < 16; ++m) oh[m] = f2bf(lds[w][m][n]);
    uint4* dh = (uint4*)(WhT + (size_t)n * NGENE + m0);
    dh[0] = ((uint4*)oh)[0]; dh[1] = ((uint4*)oh)[1];
  }
}

// ---------- fused masked exp-GEMM, barrier-free, pipelined ------------------
// 4 independent waves/block, 32 m-rows each. B double-buffered in REGISTERS
// 1 step ahead; adj+w2 2 steps ahead. Issue order per step:
//   [B(st+1)] [af-compute consumes adj(st)] [adj(st+2)] [MFMA consumes B(st)]
// With in-order vmcnt, every wait leaves >=14 loads outstanding -> no drain.
__global__ __launch_bounds__(256, 2) void k_att(
    const void* __restrict__ adj, const int* __restrict__ flag,
    const unsigned short* __restrict__ WhT,
    const float* __restrict__ w1, const float* __restrict__ w2,
    float* __restrict__ Opart, float* __restrict__ Spart) {
  const int tid = threadIdx.x;
  const int w = tid >> 6, l = tid & 63;
  const int q = l >> 4, ln = l & 15;
  const int mb = blockIdx.x & 63;
  const int kc = blockIdx.x >> 6;
  const int m0 = mb * 128 + w * 32;
  const int r0 = m0 + ln, r1 = m0 + 16 + ln;
  const int kbase = kc * KCHUNK;

  const float w1v0 = w1[r0], w1v1 = w1[r1];

  const unsigned short* bpt[8];
#pragma unroll
  for (int t = 0; t < 8; ++t)
    bpt[t] = WhT + (size_t)(16 * t + ln) * NGENE + kbase + q * 8;

  f32x4 acc0[8], acc1[8];
#pragma unroll
  for (int t = 0; t < 8; ++t) {
    acc0[t] = (f32x4){0.f, 0.f, 0.f, 0.f};
    acc1[t] = (f32x4){0.f, 0.f, 0.f, 0.f};
  }
  float ssum0 = 0.f, ssum1 = 0.f;
  const float* wp = w2 + kbase + q * 8;

  // B register double-buffer, preload step 0
  bf16x8 bbuf[2][8];
#pragma unroll
  for (int t = 0; t < 8; ++t) bbuf[0][t] = *(const bf16x8*)(bpt[t]);

  if (*flag) {   // -------- bf16 adjacency --------
    const unsigned short* A = (const unsigned short*)adj;
    const unsigned short* ap0 = A + (size_t)r0 * NGENE + kbase + q * 8;
    const unsigned short* ap1 = A + (size_t)r1 * NGENE + kbase + q * 8;
    uint4 c0[2], c1[2]; f32x4 wa[2], wb[2];
#pragma unroll
    for (int i = 0; i < 2; ++i) {
      c0[i] = *(const uint4*)(ap0 + i * 32);
      c1[i] = *(const uint4*)(ap1 + i * 32);
      wa[i] = *(const f32x4*)(wp + i * 32);
      wb[i] = *(const f32x4*)(wp + i * 32 + 4);
    }
#pragma unroll 2
    for (int st = 0; st < NSTEP; ++st) {
      const int cur = st & 1;
      // (1) issue B loads for st+1
      if (st + 1 < NSTEP) {
#pragma unroll
        for (int t = 0; t < 8; ++t)
          bbuf[cur ^ 1][t] = *(const bf16x8*)(bpt[t] + (st + 1) * 32);
      }
      // (2) af from adj(st) (issued 2 steps ago)
      uint4 u0 = c0[cur], u1 = c1[cur];
      f32x4 va = wa[cur], vb = wb[cur];
      bf16x8 af0, af1;
      const unsigned int* p0w = (const unsigned int*)&u0;
      const unsigned int* p1w = (const unsigned int*)&u1;
#pragma unroll
      for (int j = 0; j < 8; ++j) {
        union { unsigned int i; float f; } x, y;
        x.i = (j & 1) ? (p0w[j >> 1] & 0xffff0000u) : (p0w[j >> 1] << 16);
        y.i = (j & 1) ? (p1w[j >> 1] & 0xffff0000u) : (p1w[j >> 1] << 16);
        const float w2v = (j < 4) ? va[j] : vb[j - 4];
        float s0 = w1v0 + w2v;
        float p0 = x.f * __expf(fmaxf(s0, ALPHA * s0));
        __bf16 pb0 = (__bf16)p0;
        af0[j] = pb0; ssum0 += (float)pb0;
        float s1 = w1v1 + w2v;
        float p1 = y.f * __expf(fmaxf(s1, ALPHA * s1));
        __bf16 pb1 = (__bf16)p1;
        af1[j] = pb1; ssum1 += (float)pb1;
      }
      // (3) issue adj/w2 loads for st+2
      if (st + 2 < NSTEP) {
        c0[cur] = *(const uint4*)(ap0 + (st + 2) * 32);
        c1[cur] = *(const uint4*)(ap1 + (st + 2) * 32);
        wa[cur] = *(const f32x4*)(wp + (st + 2) * 32);
        wb[cur] = *(const f32x4*)(wp + (st + 2) * 32 + 4);
      }
      // (4) MFMA consumes B(st) (issued 1 step ago)
#pragma unroll
      for (int t = 0; t < 8; ++t) {
        acc0[t] = __builtin_amdgcn_mfma_f32_16x16x32_bf16(af0, bbuf[cur][t], acc0[t], 0, 0, 0);
        acc1[t] = __builtin_amdgcn_mfma_f32_16x16x32_bf16(af1, bbuf[cur][t], acc1[t], 0, 0, 0);
      }
    }
  } else {       // -------- f32 adjacency --------
    const float* A = (const float*)adj;
    const float* ap0 = A + (size_t)r0 * NGENE + kbase + q * 8;
    const float* ap1 = A + (size_t)r1 * NGENE + kbase + q * 8;
    f32x4 c0a[2], c0b[2], c1a[2], c1b[2], wa[2], wb[2];
#pragma unroll
    for (int i = 0; i < 2; ++i) {
      c0a[i] = *(const f32x4*)(ap0 + i * 32);
      c0b[i] = *(const f32x4*)(ap0 + i * 32 + 4);
      c1a[i] = *(const f32x4*)(ap1 + i * 32);
      c1b[i] = *(const f32x4*)(ap1 + i * 32 + 4);
      wa[i] = *(const f32x4*)(wp + i * 32);
      wb[i] = *(const f32x4*)(wp + i * 32 + 4);
    }
#pragma unroll 2
    for (int st = 0; st < NSTEP; ++st) {
      const int cur = st & 1;
      // (1) issue B loads for st+1
      if (st + 1 < NSTEP) {
#pragma unroll
        for (int t = 0; t < 8; ++t)
          bbuf[cur ^ 1][t] = *(const bf16x8*)(bpt[t] + (st + 1) * 32);
      }
      // (2) af from adj(st)
      f32x4 u0a = c0a[cur], u0b = c0b[cur], u1a = c1a[cur], u1b = c1b[cur];
      f32x4 va = wa[cur], vb = wb[cur];
      bf16x8 af0, af1;
#pragma unroll
      for (int j = 0; j < 8; ++j) {
        const float a0 = (j < 4) ? u0a[j] : u0b[j - 4];
        const float a1 = (j < 4) ? u1a[j] : u1b[j - 4];
        const float w2v = (j < 4) ? va[j] : vb[j - 4];
        float s0 = w1v0 + w2v;
        float p0 = a0 * __expf(fmaxf(s0, ALPHA * s0));
        __bf16 pb0 = (__bf16)p0;
        af0[j] = pb0; ssum0 += (float)pb0;
        float s1 = w1v1 + w2v;
        float p1 = a1 * __expf(fmaxf(s1, ALPHA * s1));
        __bf16 pb1 = (__bf16)p1;
        af1[j] = pb1; ssum1 += (float)pb1;
      }
      // (3) issue adj/w2 loads for st+2
      if (st + 2 < NSTEP) {
        c0a[cur] = *(const f32x4*)(ap0 + (st + 2) * 32);
        c0b[cur] = *(const f32x4*)(ap0 + (st + 2) * 32 + 4);
        c1a[cur] = *(const f32x4*)(ap1 + (st + 2) * 32);
        c1b[cur] = *(const f32x4*)(ap1 + (st + 2) * 32 + 4);
        wa[cur] = *(const f32x4*)(wp + (st + 2) * 32);
        wb[cur] = *(const f32x4*)(wp + (st + 2) * 32 + 4);
      }
      // (4) MFMA consumes B(st)
#pragma unroll
      for (int t = 0; t < 8; ++t) {
        acc0[t] = __builtin_amdgcn_mfma_f32_16x16x32_bf16(af0, bbuf[cur][t], acc0[t], 0, 0, 0);
        acc1[t] = __builtin_amdgcn_mfma_f32_16x16x32_bf16(af1, bbuf[cur][t], acc1[t], 0, 0, 0);
      }
    }
  }

  ssum0 += __shfl_xor(ssum0, 16); ssum0 += __shfl_xor(ssum0, 32);
  ssum1 += __shfl_xor(ssum1, 16); ssum1 += __shfl_xor(ssum1, 32);
  if (l < 16) {
    Spart[(size_t)kc * NREG + r0] = ssum0;
    Spart[(size_t)kc * NREG + r1] = ssum1;
  }
  float* op0 = Opart + ((size_t)kc * NREG + m0) * ODIM;
  float* op1 = op0 + 16 * ODIM;
#pragma unroll
  for (int t = 0; t < 8; ++t)
#pragma unroll
    for (int r = 0; r < 4; ++r) {
      op0[(q * 4 + r) * ODIM + 16 * t + ln] = acc0[t][r];
      op1[(q * 4 + r) * ODIM + 16 * t + ln] = acc1[t][r];
    }
}

// ---------- reduce splits, normalize, ELU, emit per detected dtype ----------
__global__ void k_red(const float* __restrict__ Opart,
                      const float* __restrict__ Spart,
                      const int* __restrict__ flag, void* __restrict__ out) {
  const int id = blockIdx.x * 256 + threadIdx.x;
  const int row = id >> 7;
  float o = 0.f, s = 0.f;
#pragma unroll
  for (int k = 0; k < KSPLIT; ++k) {
    o += Opart[(size_t)k * (NREG * ODIM) + id];
    s += Spart[(size_t)k * NREG + row];
  }
  const float r = o / s;
  const float res = r > 0.f ? r : (__expf(r) - 1.f);
  if (*flag) ((unsigned short*)out)[id] = f2bf(res);
  else       ((float*)out)[id] = res;
}

extern "C" void kernel_launch(void* const* d_in, const int* in_sizes, int n_in,
                              void* d_out, int out_size, void* d_ws, size_t ws_size,
                              hipStream_t stream) {
  const void* X   = d_in[0];
  const void* ADJ = d_in[1];
  const void* W   = d_in[2];
  const void* AV  = d_in[3];

  char* ws = (char*)d_ws;
  size_t off = 0;
  auto alloc = [&](size_t bytes) -> void* {
    void* p = ws + off; off += (bytes + 255) & ~(size_t)255; return p;
  };
  unsigned short* WhT = (unsigned short*)alloc((size_t)ODIM * NGENE * 2);
  unsigned short* WT  = (unsigned short*)alloc((size_t)DMODEL * ODIM * 2);
  float* AVf   = (float*)alloc(2 * ODIM * 4);
  float* w1    = (float*)alloc((size_t)NREG * 4);
  float* w2    = (float*)alloc((size_t)NGENE * 4);
  int*   flag  = (int*)alloc(256);
  float* Spart = (float*)alloc((size_t)KSPLIT * NREG * 4);
  float* Opart = (float*)alloc((size_t)KSPLIT * NREG * ODIM * 4);

  hipLaunchKernelGGL(k_detect, dim3(1), dim3(64), 0, stream,
                     (const unsigned int*)ADJ, flag);
  hipLaunchKernelGGL(k_wt, dim3(ODIM), dim3(DMODEL), 0, stream,
                     W, AV, flag, WT, AVf);
  hipLaunchKernelGGL(k_wh, dim3(NGENE / 64), dim3(256), 0, stream,
                     X, flag, WT, AVf, WhT, w1, w2);
  hipLaunchKernelGGL(k_att, dim3(64 * KSPLIT), dim3(256), 0, stream,
                     ADJ, flag, WhT, w1, w2, Opart, Spart);
  hipLaunchKernelGGL(k_red, dim3((NREG * ODIM) / 256), dim3(256), 0, stream,
                     Opart, Spart, flag, d_out);
}

// Round 6
// 751.624 us; speedup vs baseline: 1.0847x; 1.0666x over previous
//
#include <hip/hip_runtime.h>
#include <hip/hip_bf16.h>

typedef __bf16 bf16x8 __attribute__((ext_vector_type(8)));
typedef float  f32x4  __attribute__((ext_vector_type(4)));

#define NGENE  16384
#define NREG   8192
#define DMODEL 256
#define ODIM   128
#define KSPLIT 8
#define KCHUNK (NGENE / KSPLIT)      // 2048
#define NSTEP  (KCHUNK / 32)         // 64
#define ALPHA  0.2f

__device__ __forceinline__ float bf2f(unsigned short u) {
  union { unsigned int i; float f; } v; v.i = ((unsigned int)u) << 16; return v.f;
}
__device__ __forceinline__ unsigned short f2bf(float f) {
  __bf16 b = (__bf16)f;
  return __builtin_bit_cast(unsigned short, b);
}
__device__ __forceinline__ void gl_lds16(const void* g, void* l) {
  __builtin_amdgcn_global_load_lds(
      (const __attribute__((address_space(1))) unsigned int*)g,
      (__attribute__((address_space(3))) unsigned int*)l, 16, 0, 0);
}

// ---------- dtype detector: adj values are exactly 0.0/1.0 ------------------
__global__ void k_detect(const unsigned int* __restrict__ adj_raw,
                         int* __restrict__ flag) {
  int found = 0;
  for (int i = threadIdx.x; i < 1024; i += 64)
    if ((adj_raw[i] & 0xffffu) == 0x3f80u) found = 1;
  int any = __any(found) ? 1 : 0;
  if (threadIdx.x == 0) *flag = any;
}

// ---------- canon W -> WT bf16 [128][256]; AV -> f32[256] -------------------
__global__ void k_wt(const void* __restrict__ W, const void* __restrict__ AVin,
                     const int* __restrict__ flag,
                     unsigned short* __restrict__ WT,
                     float* __restrict__ AVf) {
  const int n = blockIdx.x, k = threadIdx.x;
  const int bf = *flag;
  float w = bf ? bf2f(((const unsigned short*)W)[k * ODIM + n])
               : ((const float*)W)[k * ODIM + n];
  WT[n * DMODEL + k] = f2bf(w);
  if (n == 0)
    AVf[k] = bf ? bf2f(((const unsigned short*)AVin)[k]) : ((const float*)AVin)[k];
}

// ---------- w_h = X@W ; WhT bf16 [128][16384]; w1,w2 f32 --------------------
__global__ __launch_bounds__(256) void k_wh(
    const void* __restrict__ X, const int* __restrict__ flag,
    const unsigned short* __restrict__ WT, const float* __restrict__ AVf,
    unsigned short* __restrict__ WhT,
    float* __restrict__ w1, float* __restrict__ w2) {
  __shared__ float lds[4][16][ODIM + 1];
  const int tid = threadIdx.x;
  const int w = tid >> 6, l = tid & 63;
  const int q = l >> 4, ln = l & 15;
  const int m0 = blockIdx.x * 64 + w * 16;

  f32x4 acc[8];
#pragma unroll
  for (int t = 0; t < 8; ++t) acc[t] = (f32x4){0.f, 0.f, 0.f, 0.f};

  const int bf = *flag;
#pragma unroll
  for (int ks = 0; ks < 8; ++ks) {
    const int k0 = ks * 32 + q * 8;
    bf16x8 a;
    if (bf) {
      a = *(const bf16x8*)((const unsigned short*)X + (size_t)(m0 + ln) * DMODEL + k0);
    } else {
      const float* xp = (const float*)X + (size_t)(m0 + ln) * DMODEL + k0;
      f32x4 x0 = *(const f32x4*)xp, x1 = *(const f32x4*)(xp + 4);
#pragma unroll
      for (int j = 0; j < 8; ++j) a[j] = (__bf16)((j < 4) ? x0[j] : x1[j - 4]);
    }
#pragma unroll
    for (int t = 0; t < 8; ++t) {
      bf16x8 b = *(const bf16x8*)(WT + (size_t)(16 * t + ln) * DMODEL + k0);
      acc[t] = __builtin_amdgcn_mfma_f32_16x16x32_bf16(a, b, acc[t], 0, 0, 0);
    }
  }

  // w1/w2 dot products with f32 a_values
  float a1v[8], a2v[8];
#pragma unroll
  for (int t = 0; t < 8; ++t) {
    a1v[t] = AVf[16 * t + ln];
    a2v[t] = AVf[ODIM + 16 * t + ln];
  }
#pragma unroll
  for (int r = 0; r < 4; ++r) {
    float s1 = 0.f, s2 = 0.f;
#pragma unroll
    for (int t = 0; t < 8; ++t) {
      s1 += acc[t][r] * a1v[t];
      s2 += acc[t][r] * a2v[t];
    }
    s1 += __shfl_xor(s1, 1); s1 += __shfl_xor(s1, 2);
    s1 += __shfl_xor(s1, 4); s1 += __shfl_xor(s1, 8);
    s2 += __shfl_xor(s2, 1); s2 += __shfl_xor(s2, 2);
    s2 += __shfl_xor(s2, 4); s2 += __shfl_xor(s2, 8);
    const int row = m0 + q * 4 + r;
    if (ln == 0) {
      w2[row] = s2;
      if (row < NREG) w1[row] = s1;
    }
  }

  // transpose via LDS -> WhT bf16
#pragma unroll
  for (int t = 0; t < 8; ++t)
#pragma unroll
    for (int r = 0; r < 4; ++r)
      lds[w][q * 4 + r][16 * t + ln] = acc[t][r];
  __syncthreads();

#pragma unroll
  for (int rr = 0; rr < 2; ++rr) {
    const int n = 2 * l + rr;
    unsigned short oh[16];
#pragma unroll
    for (int m = 0; m < 16; ++m) oh[m] = f2bf(lds[w][m][n]);
    uint4* dh = (uint4*)(WhT + (size_t)n * NGENE + m0);
    dh[0] = ((uint4*)oh)[0]; dh[1] = ((uint4*)oh)[1];
  }
}

// ---------- fused masked exp-GEMM (R3 structure: LDS dbuf + barrier) --------
__device__ __forceinline__ void att_compute(
    const float* av0, const float* av1, const float* w2v,
    const unsigned char* lsb, int q, int ln, float w1v0, float w1v1,
    f32x4* acc0, f32x4* acc1, float& ssum0, float& ssum1) {
  bf16x8 af0, af1;
#pragma unroll
  for (int j = 0; j < 8; ++j) {
    float s0 = w1v0 + w2v[j];
    float p0 = av0[j] * __expf(fmaxf(s0, ALPHA * s0));
    __bf16 pb0 = (__bf16)p0;
    af0[j] = pb0; ssum0 += (float)pb0;
    float s1 = w1v1 + w2v[j];
    float p1 = av1[j] * __expf(fmaxf(s1, ALPHA * s1));
    __bf16 pb1 = (__bf16)p1;
    af1[j] = pb1; ssum1 += (float)pb1;
  }
#pragma unroll
  for (int t = 0; t < 8; ++t) {
    int n = 16 * t + ln;
    int s = n * 4 + (q ^ ((n >> 1) & 3));
    bf16x8 b = *(const bf16x8*)(lsb + s * 16);
    acc0[t] = __builtin_amdgcn_mfma_f32_16x16x32_bf16(af0, b, acc0[t], 0, 0, 0);
    acc1[t] = __builtin_amdgcn_mfma_f32_16x16x32_bf16(af1, b, acc1[t], 0, 0, 0);
  }
}

// block: 256 thr = 4 waves; wave covers 32 m-rows; block 128 m-rows x KCHUNK.
__global__ __launch_bounds__(256) void k_att(
    const void* __restrict__ adj, const int* __restrict__ flag,
    const unsigned short* __restrict__ WhT,
    const float* __restrict__ w1, const float* __restrict__ w2,
    float* __restrict__ Opart, float* __restrict__ Spart) {
  __shared__ __align__(16) unsigned char ls[2][8192];
  const int tid = threadIdx.x;
  const int w = tid >> 6, l = tid & 63;
  const int q = l >> 4, ln = l & 15;
  const int mb = blockIdx.x & 63;
  const int kc = blockIdx.x >> 6;
  const int m0 = mb * 128 + w * 32;
  const int r0 = m0 + ln, r1 = m0 + 16 + ln;
  const int kbase = kc * KCHUNK;

  const float w1v0 = w1[r0], w1v1 = w1[r1];

  // staging: slot s (0..511) holds 8 bf16 of row n=s>>2 at k-quad qs=(s&3)^((n>>1)&3)
  size_t soff[2];
  int ldsoff[2];
#pragma unroll
  for (int i = 0; i < 2; ++i) {
    int s = i * 256 + tid;
    int n = s >> 2;
    int qs = (s & 3) ^ ((n >> 1) & 3);
    soff[i] = (size_t)n * NGENE + qs * 8;
    ldsoff[i] = (i * 256 + w * 64) * 16;    // wave-uniform base; HW adds lane*16
  }
  auto stage = [&](int kglob, int buf) {
#pragma unroll
    for (int i = 0; i < 2; ++i)
      gl_lds16(WhT + soff[i] + kglob, &ls[buf][ldsoff[i]]);
  };

  f32x4 acc0[8], acc1[8];
#pragma unroll
  for (int t = 0; t < 8; ++t) {
    acc0[t] = (f32x4){0.f, 0.f, 0.f, 0.f};
    acc1[t] = (f32x4){0.f, 0.f, 0.f, 0.f};
  }
  float ssum0 = 0.f, ssum1 = 0.f;
  const float* wp = w2 + kbase + q * 8;

  stage(kbase, 0);

  if (*flag) {   // -------- bf16 adjacency --------
    const unsigned short* A = (const unsigned short*)adj;
    const unsigned short* ap0 = A + (size_t)r0 * NGENE + kbase + q * 8;
    const unsigned short* ap1 = A + (size_t)r1 * NGENE + kbase + q * 8;
    uint4 c0 = *(const uint4*)ap0;
    uint4 c1 = *(const uint4*)ap1;
    f32x4 wa = *(const f32x4*)wp, wb = *(const f32x4*)(wp + 4);
    for (int st = 0; st < NSTEP; ++st) {
      __syncthreads();                       // stage(st) complete
      if (st + 1 < NSTEP) stage(kbase + (st + 1) * 32, (st + 1) & 1);
      uint4 u0 = c0, u1 = c1; f32x4 va = wa, vb = wb;
      if (st + 1 < NSTEP) {
        c0 = *(const uint4*)(ap0 + (st + 1) * 32);
        c1 = *(const uint4*)(ap1 + (st + 1) * 32);
        wa = *(const f32x4*)(wp + (st + 1) * 32);
        wb = *(const f32x4*)(wp + (st + 1) * 32 + 4);
      }
      float av0[8], av1[8], w2v[8];
      const unsigned int* p0w = (const unsigned int*)&u0;
      const unsigned int* p1w = (const unsigned int*)&u1;
#pragma unroll
      for (int j = 0; j < 8; ++j) {
        union { unsigned int i; float f; } x, y;
        x.i = (j & 1) ? (p0w[j >> 1] & 0xffff0000u) : (p0w[j >> 1] << 16);
        y.i = (j & 1) ? (p1w[j >> 1] & 0xffff0000u) : (p1w[j >> 1] << 16);
        av0[j] = x.f; av1[j] = y.f;
        w2v[j] = (j < 4) ? va[j] : vb[j - 4];
      }
      att_compute(av0, av1, w2v, ls[st & 1], q, ln, w1v0, w1v1,
                  acc0, acc1, ssum0, ssum1);
    }
  } else {       // -------- f32 adjacency --------
    const float* A = (const float*)adj;
    const float* ap0 = A + (size_t)r0 * NGENE + kbase + q * 8;
    const float* ap1 = A + (size_t)r1 * NGENE + kbase + q * 8;
    f32x4 c0a = *(const f32x4*)ap0, c0b = *(const f32x4*)(ap0 + 4);
    f32x4 c1a = *(const f32x4*)ap1, c1b = *(const f32x4*)(ap1 + 4);
    f32x4 wa = *(const f32x4*)wp, wb = *(const f32x4*)(wp + 4);
    for (int st = 0; st < NSTEP; ++st) {
      __syncthreads();
      if (st + 1 < NSTEP) stage(kbase + (st + 1) * 32, (st + 1) & 1);
      f32x4 u0a = c0a, u0b = c0b, u1a = c1a, u1b = c1b;
      f32x4 va = wa, vb = wb;
      if (st + 1 < NSTEP) {
        c0a = *(const f32x4*)(ap0 + (st + 1) * 32);
        c0b = *(const f32x4*)(ap0 + (st + 1) * 32 + 4);
        c1a = *(const f32x4*)(ap1 + (st + 1) * 32);
        c1b = *(const f32x4*)(ap1 + (st + 1) * 32 + 4);
        wa = *(const f32x4*)(wp + (st + 1) * 32);
        wb = *(const f32x4*)(wp + (st + 1) * 32 + 4);
      }
      float av0[8], av1[8], w2v[8];
#pragma unroll
      for (int j = 0; j < 8; ++j) {
        av0[j] = (j < 4) ? u0a[j] : u0b[j - 4];
        av1[j] = (j < 4) ? u1a[j] : u1b[j - 4];
        w2v[j] = (j < 4) ? va[j] : vb[j - 4];
      }
      att_compute(av0, av1, w2v, ls[st & 1], q, ln, w1v0, w1v1,
                  acc0, acc1, ssum0, ssum1);
    }
  }

  ssum0 += __shfl_xor(ssum0, 16); ssum0 += __shfl_xor(ssum0, 32);
  ssum1 += __shfl_xor(ssum1, 16); ssum1 += __shfl_xor(ssum1, 32);
  if (l < 16) {
    Spart[(size_t)kc * NREG + r0] = ssum0;
    Spart[(size_t)kc * NREG + r1] = ssum1;
  }
  float* op0 = Opart + ((size_t)kc * NREG + m0) * ODIM;
  float* op1 = op0 + 16 * ODIM;
#pragma unroll
  for (int t = 0; t < 8; ++t)
#pragma unroll
    for (int r = 0; r < 4; ++r) {
      op0[(q * 4 + r) * ODIM + 16 * t + ln] = acc0[t][r];
      op1[(q * 4 + r) * ODIM + 16 * t + ln] = acc1[t][r];
    }
}

// ---------- reduce splits, normalize, ELU, emit per detected dtype ----------
// 4 elements per thread, f32x4 vector loads on the 33 MB Opart stream.
__global__ void k_red(const float* __restrict__ Opart,
                      const float* __restrict__ Spart,
                      const int* __restrict__ flag, void* __restrict__ out) {
  const int id4 = blockIdx.x * 256 + threadIdx.x;   // 0 .. 8192*128/4-1
  const int id = id4 * 4;
  const int row = id >> 7;
  f32x4 o = (f32x4){0.f, 0.f, 0.f, 0.f};
  float s = 0.f;
#pragma unroll
  for (int k = 0; k < KSPLIT; ++k) {
    f32x4 v = *(const f32x4*)(Opart + (size_t)k * (NREG * ODIM) + id);
    o += v;
    s += Spart[(size_t)k * NREG + row];
  }
  const float inv = 1.f / s;
  if (*flag) {
    unsigned short r4[4];
#pragma unroll
    for (int j = 0; j < 4; ++j) {
      const float r = o[j] * inv;
      r4[j] = f2bf(r > 0.f ? r : (__expf(r) - 1.f));
    }
    *(uint2*)((unsigned short*)out + id) = *(uint2*)r4;
  } else {
    f32x4 r4;
#pragma unroll
    for (int j = 0; j < 4; ++j) {
      const float r = o[j] * inv;
      r4[j] = r > 0.f ? r : (__expf(r) - 1.f);
    }
    *(f32x4*)((float*)out + id) = r4;
  }
}

extern "C" void kernel_launch(void* const* d_in, const int* in_sizes, int n_in,
                              void* d_out, int out_size, void* d_ws, size_t ws_size,
                              hipStream_t stream) {
  const void* X   = d_in[0];
  const void* ADJ = d_in[1];
  const void* W   = d_in[2];
  const void* AV  = d_in[3];

  char* ws = (char*)d_ws;
  size_t off = 0;
  auto alloc = [&](size_t bytes) -> void* {
    void* p = ws + off; off += (bytes + 255) & ~(size_t)255; return p;
  };
  unsigned short* WhT = (unsigned short*)alloc((size_t)ODIM * NGENE * 2);
  unsigned short* WT  = (unsigned short*)alloc((size_t)DMODEL * ODIM * 2);
  float* AVf   = (float*)alloc(2 * ODIM * 4);
  float* w1    = (float*)alloc((size_t)NREG * 4);
  float* w2    = (float*)alloc((size_t)NGENE * 4);
  int*   flag  = (int*)alloc(256);
  float* Spart = (float*)alloc((size_t)KSPLIT * NREG * 4);
  float* Opart = (float*)alloc((size_t)KSPLIT * NREG * ODIM * 4);

  hipLaunchKernelGGL(k_detect, dim3(1), dim3(64), 0, stream,
                     (const unsigned int*)ADJ, flag);
  hipLaunchKernelGGL(k_wt, dim3(ODIM), dim3(DMODEL), 0, stream,
                     W, AV, flag, WT, AVf);
  hipLaunchKernelGGL(k_wh, dim3(NGENE / 64), dim3(256), 0, stream,
                     X, flag, WT, AVf, WhT, w1, w2);
  hipLaunchKernelGGL(k_att, dim3(64 * KSPLIT), dim3(256), 0, stream,
                     ADJ, flag, WhT, w1, w2, Opart, Spart);
  hipLaunchKernelGGL(k_red, dim3((NREG * ODIM) / 1024), dim3(256), 0, stream,
                     Opart, Spart, flag, d_out);
}